// Round 1
// baseline (415.622 us; speedup 1.0000x reference)
//
#include <hip/hip_runtime.h>

constexpr int RESI   = 128;
constexpr int NSTEPS = 512;

__global__ __launch_bounds__(128) void occ_march_kernel(
    const int*   __restrict__ occ,        // [4,128,128,128] int32 (bool 0/1)
    const float* __restrict__ rays_o,     // [N,3]
    const float* __restrict__ rays_d,     // [N,3]
    const int*   __restrict__ rays_bidx,  // [N]
    float*       __restrict__ out_pts,    // [N,512,3]
    float*       __restrict__ out_t,      // [N,512]
    float*       __restrict__ out_mask,   // [N,512] as 0.0/1.0
    int n_rays)
{
#pragma clang fp contract(off)
    const int ray = blockIdx.x;
    if (ray >= n_rays) return;

    const float ox = rays_o[3 * ray + 0];
    const float oy = rays_o[3 * ray + 1];
    const float oz = rays_o[3 * ray + 2];
    const float dx = rays_d[3 * ray + 0];
    const float dy = rays_d[3 * ray + 1];
    const float dz = rays_d[3 * ray + 2];
    const int   b  = rays_bidx[ray];

    // safe_d / inv_d exactly as the reference (fp32 IEEE div, no fast-math)
    const float eps = 1e-10f;
    const float sdx = (fabsf(dx) < eps) ? ((dx >= 0.0f) ? eps : -eps) : dx;
    const float sdy = (fabsf(dy) < eps) ? ((dy >= 0.0f) ? eps : -eps) : dy;
    const float sdz = (fabsf(dz) < eps) ? ((dz >= 0.0f) ? eps : -eps) : dz;
    const float invx = 1.0f / sdx;
    const float invy = 1.0f / sdy;
    const float invz = 1.0f / sdz;

    const float t0x = (-1.0f - ox) * invx;
    const float t1x = ( 1.0f - ox) * invx;
    const float t0y = (-1.0f - oy) * invy;
    const float t1y = ( 1.0f - oy) * invy;
    const float t0z = (-1.0f - oz) * invz;
    const float t1z = ( 1.0f - oz) * invz;

    const float tmin = fmaxf(fmaxf(fminf(t0x, t1x), fminf(t0y, t1y)), fminf(t0z, t1z));
    const float tmax = fminf(fminf(fmaxf(t0x, t1x), fmaxf(t0y, t1y)), fmaxf(t0z, t1z));
    const float nearv  = fmaxf(tmin, 0.0f);
    const bool  ray_ok = (tmax > nearv);

    const int* __restrict__ g = occ + (size_t)b * (RESI * RESI * RESI);

    const int s0 = (int)threadIdx.x * 4;   // 128 threads x 4 steps = 512

    float tv[4], mv[4], p[12];

#pragma unroll
    for (int i = 0; i < 4; ++i) {
        const int   s  = s0 + i;
        // t = near + (s + 0.5)*STEP  -- mul then add, NOT fused (pragma above)
        const float ts = nearv + ((float)s + 0.5f) * 0.005f;
        // pts = o + t*d  -- mul then add, NOT fused
        const float px = ox + ts * dx;
        const float py = oy + ts * dy;
        const float pz = oz + ts * dz;

        const bool in_box = ray_ok && (ts < tmax);

        // gidx = clip(int((p*0.5+0.5)*128), 0, 127); (int) truncates toward 0 like astype
        int gx = (int)((px * 0.5f + 0.5f) * 128.0f);
        int gy = (int)((py * 0.5f + 0.5f) * 128.0f);
        int gz = (int)((pz * 0.5f + 0.5f) * 128.0f);
        gx = min(max(gx, 0), RESI - 1);
        gy = min(max(gy, 0), RESI - 1);
        gz = min(max(gz, 0), RESI - 1);

        const int  o = g[(gx * RESI + gy) * RESI + gz];
        const bool m = in_box && (o != 0);

        tv[i] = ts;
        mv[i] = m ? 1.0f : 0.0f;
        p[3 * i + 0] = m ? px : 0.0f;
        p[3 * i + 1] = m ? py : 0.0f;
        p[3 * i + 2] = m ? pz : 0.0f;
    }

    const size_t base = (size_t)ray * NSTEPS + (size_t)s0;

    *(float4*)(out_t    + base) = make_float4(tv[0], tv[1], tv[2], tv[3]);
    *(float4*)(out_mask + base) = make_float4(mv[0], mv[1], mv[2], mv[3]);

    float4* pp = (float4*)(out_pts + base * 3);   // 48B-aligned per lane
    pp[0] = make_float4(p[0], p[1], p[2],  p[3]);
    pp[1] = make_float4(p[4], p[5], p[6],  p[7]);
    pp[2] = make_float4(p[8], p[9], p[10], p[11]);
}

extern "C" void kernel_launch(void* const* d_in, const int* in_sizes, int n_in,
                              void* d_out, int out_size, void* d_ws, size_t ws_size,
                              hipStream_t stream) {
    const int*   occ    = (const int*)  d_in[0];  // bool -> int32 per harness contract
    const float* rays_o = (const float*)d_in[1];
    const float* rays_d = (const float*)d_in[2];
    const int*   bidx   = (const int*)  d_in[3];
    // d_in[4] = max_steps (always 512 in this problem; layout depends on it being 512)

    const int n_rays = in_sizes[3];

    float* out      = (float*)d_out;
    float* out_pts  = out;                                    // [N,512,3]
    float* out_t    = out + (size_t)n_rays * NSTEPS * 3;      // [N,512]
    float* out_mask = out_t + (size_t)n_rays * NSTEPS;        // [N,512]

    occ_march_kernel<<<n_rays, 128, 0, stream>>>(occ, rays_o, rays_d, bidx,
                                                 out_pts, out_t, out_mask, n_rays);
}

// Round 2
// 372.500 us; speedup vs baseline: 1.1158x; 1.1158x over previous
//
#include <hip/hip_runtime.h>

constexpr int RESI   = 128;
constexpr int NSTEPS = 512;
constexpr int GRID_WORDS_PER_BATCH = RESI * RESI * RESI / 32;  // 65536 u32 per batch

// Pack int32 0/1 occupancy -> bitfield. One wave packs 64 consecutive voxels
// via __ballot into a single u64 store.
__global__ __launch_bounds__(256) void occ_pack_kernel(
    const int* __restrict__ occ, unsigned long long* __restrict__ bits)
{
    const int e    = blockIdx.x * blockDim.x + threadIdx.x;   // voxel linear index
    const int lane = threadIdx.x & 63;
    const bool pred = (occ[e] != 0);
    const unsigned long long m = __ballot(pred);
    if (lane == 0) bits[e >> 6] = m;
}

__global__ __launch_bounds__(128) void occ_march_kernel(
    const unsigned int* __restrict__ gridbits,  // [4, 128*128*128/32] packed
    const float* __restrict__ rays_o,           // [N,3]
    const float* __restrict__ rays_d,           // [N,3]
    const int*   __restrict__ rays_bidx,        // [N]
    float*       __restrict__ out_pts,          // [N,512,3]
    float*       __restrict__ out_t,            // [N,512]
    float*       __restrict__ out_mask,         // [N,512] as 0.0/1.0
    int n_rays)
{
#pragma clang fp contract(off)
    const int ray = blockIdx.x;
    if (ray >= n_rays) return;

    const float ox = rays_o[3 * ray + 0];
    const float oy = rays_o[3 * ray + 1];
    const float oz = rays_o[3 * ray + 2];
    const float dx = rays_d[3 * ray + 0];
    const float dy = rays_d[3 * ray + 1];
    const float dz = rays_d[3 * ray + 2];
    const int   b  = rays_bidx[ray];

    // safe_d / inv_d exactly as the reference (fp32 IEEE div, no fast-math)
    const float eps = 1e-10f;
    const float sdx = (fabsf(dx) < eps) ? ((dx >= 0.0f) ? eps : -eps) : dx;
    const float sdy = (fabsf(dy) < eps) ? ((dy >= 0.0f) ? eps : -eps) : dy;
    const float sdz = (fabsf(dz) < eps) ? ((dz >= 0.0f) ? eps : -eps) : dz;
    const float invx = 1.0f / sdx;
    const float invy = 1.0f / sdy;
    const float invz = 1.0f / sdz;

    const float t0x = (-1.0f - ox) * invx;
    const float t1x = ( 1.0f - ox) * invx;
    const float t0y = (-1.0f - oy) * invy;
    const float t1y = ( 1.0f - oy) * invy;
    const float t0z = (-1.0f - oz) * invz;
    const float t1z = ( 1.0f - oz) * invz;

    const float tmin = fmaxf(fmaxf(fminf(t0x, t1x), fminf(t0y, t1y)), fminf(t0z, t1z));
    const float tmax = fminf(fminf(fmaxf(t0x, t1x), fmaxf(t0y, t1y)), fmaxf(t0z, t1z));
    const float nearv  = fmaxf(tmin, 0.0f);
    const bool  ray_ok = (tmax > nearv);

    const unsigned int* __restrict__ gb = gridbits + (size_t)b * GRID_WORDS_PER_BATCH;

    const int s0 = (int)threadIdx.x * 4;   // 128 threads x 4 steps = 512

    float tv[4], mv[4], p[12];

#pragma unroll
    for (int i = 0; i < 4; ++i) {
        const int   s  = s0 + i;
        // t = near + (s + 0.5)*STEP  -- mul then add, NOT fused (pragma above)
        const float ts = nearv + ((float)s + 0.5f) * 0.005f;
        // pts = o + t*d  -- mul then add, NOT fused
        const float px = ox + ts * dx;
        const float py = oy + ts * dy;
        const float pz = oz + ts * dz;

        const bool in_box = ray_ok && (ts < tmax);

        // gidx = clip(int((p*0.5+0.5)*128), 0, 127); (int) truncates toward 0 like astype
        int gx = (int)((px * 0.5f + 0.5f) * 128.0f);
        int gy = (int)((py * 0.5f + 0.5f) * 128.0f);
        int gz = (int)((pz * 0.5f + 0.5f) * 128.0f);
        gx = min(max(gx, 0), RESI - 1);
        gy = min(max(gy, 0), RESI - 1);
        gz = min(max(gz, 0), RESI - 1);

        // linear voxel = (gx*128+gy)*128+gz; word = linear>>5, bit = gz&31
        const unsigned int word = gb[((gx << 7) + gy) * 4 + (gz >> 5)];
        const bool occ_hit = (word >> (gz & 31)) & 1u;
        const bool m = in_box && occ_hit;

        tv[i] = ts;
        mv[i] = m ? 1.0f : 0.0f;
        p[3 * i + 0] = m ? px : 0.0f;
        p[3 * i + 1] = m ? py : 0.0f;
        p[3 * i + 2] = m ? pz : 0.0f;
    }

    const size_t base = (size_t)ray * NSTEPS + (size_t)s0;

    *(float4*)(out_t    + base) = make_float4(tv[0], tv[1], tv[2], tv[3]);
    *(float4*)(out_mask + base) = make_float4(mv[0], mv[1], mv[2], mv[3]);

    float4* pp = (float4*)(out_pts + base * 3);   // 48B per lane, 3 x float4
    pp[0] = make_float4(p[0], p[1], p[2],  p[3]);
    pp[1] = make_float4(p[4], p[5], p[6],  p[7]);
    pp[2] = make_float4(p[8], p[9], p[10], p[11]);
}

extern "C" void kernel_launch(void* const* d_in, const int* in_sizes, int n_in,
                              void* d_out, int out_size, void* d_ws, size_t ws_size,
                              hipStream_t stream) {
    const int*   occ    = (const int*)  d_in[0];  // bool -> int32
    const float* rays_o = (const float*)d_in[1];
    const float* rays_d = (const float*)d_in[2];
    const int*   bidx   = (const int*)  d_in[3];

    const int n_rays = in_sizes[3];
    const int n_vox  = in_sizes[0];               // 4*128^3 = 8388608

    float* out      = (float*)d_out;
    float* out_pts  = out;                                    // [N,512,3]
    float* out_t    = out + (size_t)n_rays * NSTEPS * 3;      // [N,512]
    float* out_mask = out_t + (size_t)n_rays * NSTEPS;        // [N,512]

    unsigned long long* bits64 = (unsigned long long*)d_ws;   // 1 MB packed grid

    occ_pack_kernel<<<n_vox / 256, 256, 0, stream>>>(occ, bits64);
    occ_march_kernel<<<n_rays, 128, 0, stream>>>((const unsigned int*)bits64,
                                                 rays_o, rays_d, bidx,
                                                 out_pts, out_t, out_mask, n_rays);
}

// Round 3
// 361.978 us; speedup vs baseline: 1.1482x; 1.0291x over previous
//
#include <hip/hip_runtime.h>

constexpr int RESI   = 128;
constexpr int NSTEPS = 512;
// Tiled bitfield: 8x8x8 voxel block = 512 bits = 64 B = one cache line.
// Per batch: 16x16x16 blocks * 16 u32 = 65536 u32 (256 KB). 4 batches = 1 MB.
constexpr int GRID_WORDS_PER_BATCH = 65536;

// Pack int32 0/1 occupancy -> tiled bitfield. One thread per output u32 word.
// Word w (within batch): blockid = w>>4 = (bx*16+by)*16+bz ; wib = w&15.
//   gx = bx*8 + (wib>>1); gy base = by*8 + (wib&1)*4 (4 rows); gz = bz*8..+8.
//   bit j = a*8 + c  with gy = gybase+a, gz = gzbase+c.
__global__ __launch_bounds__(256) void occ_pack_tiled_kernel(
    const int* __restrict__ occ, unsigned int* __restrict__ bits)
{
    const int w = blockIdx.x * blockDim.x + threadIdx.x;   // global word id
    const int b   = w >> 16;
    const int rem = w & 65535;
    const int blockid = rem >> 4;
    const int wib     = rem & 15;
    const int bx = blockid >> 8;
    const int by = (blockid >> 4) & 15;
    const int bz = blockid & 15;
    const int gx  = bx * 8 + (wib >> 1);
    const int gy0 = by * 8 + (wib & 1) * 4;
    const int gz0 = bz * 8;

    const int* __restrict__ src = occ + (((size_t)b * RESI + gx) * RESI + gy0) * RESI + gz0;

    unsigned int word = 0;
#pragma unroll
    for (int a = 0; a < 4; ++a) {
        const int* row = src + a * RESI;
#pragma unroll
        for (int c = 0; c < 8; ++c)
            word |= (row[c] != 0 ? 1u : 0u) << (a * 8 + c);
    }
    bits[w] = word;
}

__global__ __launch_bounds__(128) void occ_march_kernel(
    const unsigned int* __restrict__ gridbits,  // tiled, [4, 65536]
    const float* __restrict__ rays_o,           // [N,3]
    const float* __restrict__ rays_d,           // [N,3]
    const int*   __restrict__ rays_bidx,        // [N]
    float*       __restrict__ out_pts,          // [N,512,3]
    float*       __restrict__ out_t,            // [N,512]
    float*       __restrict__ out_mask,         // [N,512] as 0.0/1.0
    int n_rays)
{
#pragma clang fp contract(off)
    const int ray = blockIdx.x;
    if (ray >= n_rays) return;

    const float ox = rays_o[3 * ray + 0];
    const float oy = rays_o[3 * ray + 1];
    const float oz = rays_o[3 * ray + 2];
    const float dx = rays_d[3 * ray + 0];
    const float dy = rays_d[3 * ray + 1];
    const float dz = rays_d[3 * ray + 2];
    const int   b  = rays_bidx[ray];

    // safe_d / inv_d exactly as the reference (fp32 IEEE div, no fast-math)
    const float eps = 1e-10f;
    const float sdx = (fabsf(dx) < eps) ? ((dx >= 0.0f) ? eps : -eps) : dx;
    const float sdy = (fabsf(dy) < eps) ? ((dy >= 0.0f) ? eps : -eps) : dy;
    const float sdz = (fabsf(dz) < eps) ? ((dz >= 0.0f) ? eps : -eps) : dz;
    const float invx = 1.0f / sdx;
    const float invy = 1.0f / sdy;
    const float invz = 1.0f / sdz;

    const float t0x = (-1.0f - ox) * invx;
    const float t1x = ( 1.0f - ox) * invx;
    const float t0y = (-1.0f - oy) * invy;
    const float t1y = ( 1.0f - oy) * invy;
    const float t0z = (-1.0f - oz) * invz;
    const float t1z = ( 1.0f - oz) * invz;

    const float tmin = fmaxf(fmaxf(fminf(t0x, t1x), fminf(t0y, t1y)), fminf(t0z, t1z));
    const float tmax = fminf(fminf(fmaxf(t0x, t1x), fmaxf(t0y, t1y)), fmaxf(t0z, t1z));
    const float nearv  = fmaxf(tmin, 0.0f);
    const bool  ray_ok = (tmax > nearv);

    const unsigned int* __restrict__ gb = gridbits + (size_t)b * GRID_WORDS_PER_BATCH;

    const int s0 = (int)threadIdx.x * 4;   // 128 threads x 4 steps = 512

    float tv[4], mv[4], p[12];

#pragma unroll
    for (int i = 0; i < 4; ++i) {
        const int   s  = s0 + i;
        // t = near + (s + 0.5)*STEP  -- mul then add, NOT fused (pragma above)
        const float ts = nearv + ((float)s + 0.5f) * 0.005f;
        // pts = o + t*d  -- mul then add, NOT fused
        const float px = ox + ts * dx;
        const float py = oy + ts * dy;
        const float pz = oz + ts * dz;

        const bool in_box = ray_ok && (ts < tmax);

        bool m = false;
        if (in_box) {   // exec-mask predication: out-of-box lanes skip the gather
            // gidx = clip(int((p*0.5+0.5)*128), 0, 127); trunc toward 0 = astype
            int gx = (int)((px * 0.5f + 0.5f) * 128.0f);
            int gy = (int)((py * 0.5f + 0.5f) * 128.0f);
            int gz = (int)((pz * 0.5f + 0.5f) * 128.0f);
            gx = min(max(gx, 0), RESI - 1);
            gy = min(max(gy, 0), RESI - 1);
            gz = min(max(gz, 0), RESI - 1);

            // tiled address: block (gx>>3,gy>>3,gz>>3) -> 16 words; see pack kernel
            const unsigned int blockid = ((unsigned)(gx >> 3) << 8) |
                                         ((unsigned)(gy >> 3) << 4) |
                                          (unsigned)(gz >> 3);
            const unsigned int wib    = (((unsigned)gx & 7u) << 1) | (((unsigned)gy >> 2) & 1u);
            const unsigned int word   = gb[(blockid << 4) | wib];
            const unsigned int bitpos = (((unsigned)gy & 3u) << 3) | ((unsigned)gz & 7u);
            m = (word >> bitpos) & 1u;
        }

        tv[i] = ts;
        mv[i] = m ? 1.0f : 0.0f;
        p[3 * i + 0] = m ? px : 0.0f;
        p[3 * i + 1] = m ? py : 0.0f;
        p[3 * i + 2] = m ? pz : 0.0f;
    }

    const size_t base = (size_t)ray * NSTEPS + (size_t)s0;

    *(float4*)(out_t    + base) = make_float4(tv[0], tv[1], tv[2], tv[3]);
    *(float4*)(out_mask + base) = make_float4(mv[0], mv[1], mv[2], mv[3]);

    float4* pp = (float4*)(out_pts + base * 3);   // 48B per lane, 3 x float4
    pp[0] = make_float4(p[0], p[1], p[2],  p[3]);
    pp[1] = make_float4(p[4], p[5], p[6],  p[7]);
    pp[2] = make_float4(p[8], p[9], p[10], p[11]);
}

extern "C" void kernel_launch(void* const* d_in, const int* in_sizes, int n_in,
                              void* d_out, int out_size, void* d_ws, size_t ws_size,
                              hipStream_t stream) {
    const int*   occ    = (const int*)  d_in[0];  // bool -> int32
    const float* rays_o = (const float*)d_in[1];
    const float* rays_d = (const float*)d_in[2];
    const int*   bidx   = (const int*)  d_in[3];

    const int n_rays = in_sizes[3];
    const int n_vox  = in_sizes[0];               // 4*128^3 = 8388608
    const int n_words = n_vox / 32;               // 262144

    float* out      = (float*)d_out;
    float* out_pts  = out;                                    // [N,512,3]
    float* out_t    = out + (size_t)n_rays * NSTEPS * 3;      // [N,512]
    float* out_mask = out_t + (size_t)n_rays * NSTEPS;        // [N,512]

    unsigned int* bits = (unsigned int*)d_ws;                 // 1 MB tiled grid

    occ_pack_tiled_kernel<<<n_words / 256, 256, 0, stream>>>(occ, bits);
    occ_march_kernel<<<n_rays, 128, 0, stream>>>(bits, rays_o, rays_d, bidx,
                                                 out_pts, out_t, out_mask, n_rays);
}